// Round 4
// baseline (1389.683 us; speedup 1.0000x reference)
//
#include <hip/hip_runtime.h>
#include <stdint.h>
#include <stddef.h>

// Conv_M: fused dynamic-filter conv. B=4, Cin=Cout=64, H=W=128, K=3.
// R9 = R8 (m201-style 2-phase-per-kk pipeline, T3+T4+T5) + final-stage
// publish fix: at ch==15, kk>=34 no new stages are issued, so vmcnt(4)
// no longer guards stage 35 -> use vmcnt(0) there (one extra drain per
// kernel). R8's bench was an infra failure ("container failed twice");
// structure is unchanged otherwise.
//   per kk (K=32): 2 phases x {ds_read quadrant ∥ 2 gll16 stage-issue ->
//   s_barrier -> lgkmcnt(0) -> setprio(1) 16 MFMA setprio(0) -> s_barrier}.
//   B-frags read once (P0), reused in P1. vmcnt(4) once per kk in P1
//   publishes stage kk+1; never drains in main loop. 3 LDS buffers,
//   2-deep prefetch. R7 (single-phase counted) measured 729 TF = the
//   "minimum 2-phase" plateau; this is the documented +18-35% step.
// k_feat / k_sw / k_gemm1 / epilogue unchanged.

using short8   = __attribute__((ext_vector_type(8))) short;
using float4v  = __attribute__((ext_vector_type(4))) float;
using ushort4v = __attribute__((ext_vector_type(4))) unsigned short;

#define DI __device__ __forceinline__

DI unsigned short f2bf(float f) {
  union { float f; unsigned int u; } a; a.f = f;
  unsigned int r = a.u + 0x7fffu + ((a.u >> 16) & 1u);
  return (unsigned short)(r >> 16);
}
DI float bf2f(unsigned short u) {
  union { unsigned int u; float f; } a; a.u = ((unsigned int)u) << 16;
  return a.f;
}
DI void gll16(const void* g, void* l) {
  __builtin_amdgcn_global_load_lds(
      (const __attribute__((address_space(1))) unsigned int*)g,
      (__attribute__((address_space(3))) unsigned int*)l, 16, 0, 0);
}

// ---------------------------------------------------------------------------
// feat layout: idx = ((kk*512 + pblk)*4 + q)*1024 + plocal*8 + j8
//   kk = k/32 (36 blocks), pblk = pixel/128 (512), q = (k>>3)&3, j8 = k&7.
// feat col = c*9 + (kh*3+kw) for x (cols 0..575), same +576 for m.
// ---------------------------------------------------------------------------
__global__ void k_feat(const float* __restrict__ x, const float* __restrict__ m,
                       unsigned short* __restrict__ featb) {
  unsigned int tid = blockIdx.x * 256u + threadIdx.x;  // < 75,497,472
  int j8   = tid & 7;
  int pl   = (tid >> 3) & 127;
  int q    = (tid >> 10) & 3;
  int pblk = (tid >> 12) & 511;
  int kk   = tid >> 21;
  int col  = kk * 32 + q * 8 + j8;
  const float* src = x;
  int jx = col;
  if (col >= 576) { src = m; jx = col - 576; }
  int c  = jx / 9;
  int t  = jx - c * 9;
  int t3 = t / 3;
  int dh = t3 - 1;
  int dw = (t - t3 * 3) - 1;
  int p  = pblk * 128 + pl;
  int b  = p >> 14, h = (p >> 7) & 127, w = p & 127;
  int hh = min(max(h + dh, 0), 127);   // replicate pad
  int ww = min(max(w + dw, 0), 127);
  featb[tid] = f2bf(src[(((b << 6) | c) << 14) + (hh << 7) + ww]);
}

// Weight swizzle: src row-major [k][n] fp32 -> bf16 B-frag tiles at
//   idx = ((k>>5)*ntiles + (n'>>4))*512 + ((k>>3)&3)*128 + (n'&15)*8 + (k&7)
// perm=1 (W2): n' = (n&63)<<6 | (n>>6)  (o-major: n' = o*64 + c).
__global__ void k_sw(const float* __restrict__ Wsrc, unsigned short* __restrict__ Wdst,
                     int ncols, int ntiles, int total, int perm) {
  int tid = blockIdx.x * 256 + threadIdx.x;
  if (tid >= total) return;
  int k = tid / ncols;
  int n = tid - k * ncols;
  int np = perm ? (((n & 63) << 6) | (n >> 6)) : n;
  int out = ((k >> 5) * ntiles + (np >> 4)) * 512 + ((k >> 3) & 3) * 128 +
            (np & 15) * 8 + (k & 7);
  Wdst[out] = f2bf(Wsrc[tid]);
}

// ---------------------------------------------------------------------------
// GEMM1: w1 = feat@W1 + b1, then yr/mr/sr[p][c] via 3x3 taps on fp32 x/m/s.
// ---------------------------------------------------------------------------
__launch_bounds__(512, 2)
__global__ void k_gemm1(const unsigned short* __restrict__ featb,
                        const unsigned short* __restrict__ W1s,
                        const float* __restrict__ b1,
                        const float* __restrict__ x, const float* __restrict__ m,
                        const float* __restrict__ s,
                        float* __restrict__ yr, float* __restrict__ mr,
                        float* __restrict__ sr) {
  __shared__ __align__(16) unsigned short Alds[4096];       // 8KB  [q][p128][j8]
  __shared__ __align__(16) unsigned short Blds[4608];       // 9216B: 9 tiles
  __shared__ __align__(16) unsigned short w1buf[128 * 152]; // 38912B
  const int tid = threadIdx.x;
  const int wv  = tid >> 6;
  const int l15 = tid & 15;
  const int q   = (tid >> 4) & 3;
  const int bm  = blockIdx.x, nb = blockIdx.y;

  float4v acc[9];
#pragma unroll
  for (int t = 0; t < 9; ++t) acc[t] = (float4v){0.f, 0.f, 0.f, 0.f};

  const unsigned short* Ab = featb + (size_t)bm * 4096;
  const unsigned short* Bb = W1s + (size_t)nb * 9 * 512;

  for (int kk = 0; kk < 36; ++kk) {
    __syncthreads();
    gll16(Ab + (size_t)kk * 2097152 + tid * 8, (char*)Alds + wv * 1024);
    gll16(Bb + (size_t)kk * 18432 + tid * 8, (char*)Blds + wv * 1024);
    if (tid < 64) gll16(Bb + (size_t)kk * 18432 + 4096 + tid * 8, (char*)Blds + 8192);
    __syncthreads();
    short8 af = *(const short8*)&Alds[q * 1024 + (16 * wv + l15) * 8];
#pragma unroll
    for (int t = 0; t < 9; ++t) {
      short8 bfr = *(const short8*)&Blds[t * 512 + q * 128 + l15 * 8];
      acc[t] = __builtin_amdgcn_mfma_f32_16x16x32_bf16(af, bfr, acc[t], 0, 0, 0);
    }
  }

  // w1 (+bias) -> LDS as bf16. C/D layout: col=lane&15, row=quad*4+i.
#pragma unroll
  for (int t = 0; t < 9; ++t) {
    int col = 16 * t + l15;
    float bb = b1[nb * 144 + col];
#pragma unroll
    for (int i = 0; i < 4; ++i) {
      int plr = 16 * wv + 4 * q + i;
      w1buf[plr * 152 + col] = f2bf(acc[t][i] + bb);
    }
  }
  __syncthreads();

  const int b = bm >> 7, h = bm & 127;  // m-block = one (b,h) image row
#pragma unroll
  for (int ii = 0; ii < 4; ++ii) {
    int task = ii * 512 + tid;     // 2048 tasks: (p 0..127) x (cl 0..15)
    int p  = task >> 4;
    int cl = task & 15;
    int c  = nb * 16 + cl;
    float w1v[9];
#pragma unroll
    for (int k = 0; k < 9; ++k) w1v[k] = bf2f(w1buf[p * 152 + cl * 9 + k]);
    size_t base = (size_t)(((b << 6) | c) << 14);
    float vy = 0.f, vm = 0.f, vs = 0.f;
#pragma unroll
    for (int dh = -1; dh <= 1; ++dh) {
      int hh = min(max(h + dh, 0), 127);
#pragma unroll
      for (int dw = -1; dw <= 1; ++dw) {
        int ww = min(max(p + dw, 0), 127);
        size_t idx = base + (hh << 7) + ww;
        int k = (dh + 1) * 3 + (dw + 1);
        float wv1 = w1v[k], aw = fabsf(wv1);
        vy += x[idx] * wv1;
        vm += m[idx] * aw;
        vs += s[idx] * aw;
      }
    }
    size_t P = (size_t)bm * 128 + p;
    yr[P * 64 + c] = vy;
    mr[P * 64 + c] = vm;
    sr[P * 64 + c] = vs;
  }
}

// ---------------------------------------------------------------------------
// GEMM2 (R9): block = 256 rows x 256 cols/chunk, 16 chunks. 512 thr = 8 waves
// 2x4: wm row-half (128 rows), wn -> o = 4ch+wn. acc[8][4] = 128 VGPR.
// K-loop: 3 LDS units (32KB each), 2-deep prefetch. Per kk, TWO phases:
//   P0: read a0..3 + b0..3 of buf[kk]; issue 2 gll16 (stage kk+2, A-half);
//       barrier; lgkmcnt(0); 16 MFMA (r0..3) in setprio(1); barrier.
//   P1: read a4..7; issue 2 gll16 (B-half); vmcnt(4) [publishes stage kk+1;
//       vmcnt(0) when ch==15 && kk>=34 since no new stages cover stage 35];
//       barrier; lgkmcnt(0); 16 MFMA (r4..7); barrier.
// Buffer hazard: gll of kk targets (kk+2)%3 = buffer read at kk-1, whose
// reads completed before kk-1's P1 post-MFMA barrier.
// ---------------------------------------------------------------------------
__launch_bounds__(512, 2)
__global__ void k_gemm2(const unsigned short* __restrict__ featb,
                        const unsigned short* __restrict__ W2s,
                        const float* __restrict__ b2,
                        const float* __restrict__ yr, const float* __restrict__ mr,
                        const float* __restrict__ sr,
                        float* __restrict__ out) {
  __shared__ __align__(16) unsigned short U[3][16384];      // 3 x 32KB: [A 8192 | B 8192]
  __shared__ __align__(16) unsigned short w2buf[256 * 68];  // 34816B, padded
  const int tid  = threadIdx.x;
  const int wv   = tid >> 6;     // 0..7
  const int lane = tid & 63;
  const int wm   = wv >> 2;      // 0..1: 128-row half
  const int wn   = wv & 3;       // 0..3: o = 4ch+wn
  const int l15  = tid & 15;
  const int q    = (tid >> 4) & 3;
  const int part = lane >> 4;    // 0..3: 16-c quarter (epilogue)
  const int bm   = blockIdx.x;   // 0..255: rows 256bm..256bm+255

  const unsigned short* Ab = featb + (size_t)bm * 8192;  // pblk 2bm,2bm+1 contiguous

  float4v acc[8][4];
#pragma unroll
  for (int r = 0; r < 8; ++r)
#pragma unroll
    for (int t = 0; t < 4; ++t) acc[r][t] = (float4v){0.f, 0.f, 0.f, 0.f};

  // prologue: stage u=0 (ch0,kk0) -> U[0], u=1 (ch0,kk1) -> U[1]
  gll16(Ab + tid * 8,                  (char*)&U[0][0]     + wv * 1024);
  gll16(Ab + 4096 + tid * 8,           (char*)&U[0][4096]  + wv * 1024);
  gll16(W2s + tid * 8,                 (char*)&U[0][8192]  + wv * 1024);
  gll16(W2s + 4096 + tid * 8,          (char*)&U[0][12288] + wv * 1024);
  gll16(Ab + 2097152 + tid * 8,        (char*)&U[1][0]     + wv * 1024);
  gll16(Ab + 2097152 + 4096 + tid * 8, (char*)&U[1][4096]  + wv * 1024);
  gll16(W2s + 131072 + tid * 8,        (char*)&U[1][8192]  + wv * 1024);
  gll16(W2s + 131072 + 4096 + tid * 8, (char*)&U[1][12288] + wv * 1024);
  // publish stage(kk=0): own oldest-4 landed, then block-wide barrier.
  asm volatile("s_waitcnt vmcnt(4)" ::: "memory");
  __builtin_amdgcn_s_barrier();

#define G2_KK(KK, BR, BS, DRAIN)                                               \
  do {                                                                         \
    const unsigned short* Al = &U[BR][0];                                      \
    const unsigned short* Bl = &U[BR][8192];                                   \
    int kks = (KK) + 2, chs = ch;                                              \
    if (kks >= 36) { kks -= 36; chs += 1; }                                    \
    const unsigned short* Ag = Ab + (size_t)kks * 2097152;                     \
    const unsigned short* Bg = W2s + (size_t)kks * 131072 + (size_t)chs * 8192;\
    /* ---- P0: read a0..3 + b0..3, stage A-half ---- */                       \
    short8 a0_[4], b_[4];                                                      \
    _Pragma("unroll") for (int r = 0; r < 4; ++r)                              \
      a0_[r] = *(const short8*)&Al[wm * 4096 + q * 1024 + r * 128 + l15 * 8];  \
    _Pragma("unroll") for (int t = 0; t < 4; ++t)                              \
      b_[t] = *(const short8*)&Bl[(4 * wn + t) * 512 + q * 128 + l15 * 8];     \
    if (chs < 16) {                                                            \
      gll16(Ag + tid * 8,        (char*)&U[BS][0]    + wv * 1024);             \
      gll16(Ag + 4096 + tid * 8, (char*)&U[BS][4096] + wv * 1024);             \
    }                                                                          \
    asm volatile("" ::: "memory");                                             \
    __builtin_amdgcn_s_barrier();                                              \
    asm volatile("s_waitcnt lgkmcnt(0)" ::: "memory");                         \
    __builtin_amdgcn_sched_barrier(0);                                         \
    __builtin_amdgcn_s_setprio(1);                                             \
    _Pragma("unroll") for (int t = 0; t < 4; ++t)                              \
      _Pragma("unroll") for (int r = 0; r < 4; ++r)                            \
        acc[r][t] = __builtin_amdgcn_mfma_f32_16x16x32_bf16(a0_[r], b_[t],     \
                                                            acc[r][t], 0, 0, 0);\
    __builtin_amdgcn_s_setprio(0);                                             \
    asm volatile("" ::: "memory");                                             \
    __builtin_amdgcn_s_barrier();                                              \
    /* ---- P1: read a4..7, stage B-half, vmcnt publish ---- */                \
    short8 a1_[4];                                                             \
    _Pragma("unroll") for (int r = 0; r < 4; ++r)                              \
      a1_[r] = *(const short8*)&Al[wm * 4096 + q * 1024 + 512 + r * 128 + l15 * 8];\
    if (chs < 16) {                                                            \
      gll16(Bg + tid * 8,        (char*)&U[BS][8192]  + wv * 1024);            \
      gll16(Bg + 4096 + tid * 8, (char*)&U[BS][12288] + wv * 1024);            \
    }                                                                          \
    if (DRAIN) { asm volatile("s_waitcnt vmcnt(0)" ::: "memory"); }            \
    else       { asm volatile("s_waitcnt vmcnt(4)" ::: "memory"); }            \
    __builtin_amdgcn_s_barrier();                                              \
    asm volatile("s_waitcnt lgkmcnt(0)" ::: "memory");                         \
    __builtin_amdgcn_sched_barrier(0);                                         \
    __builtin_amdgcn_s_setprio(1);                                             \
    _Pragma("unroll") for (int t = 0; t < 4; ++t)                              \
      _Pragma("unroll") for (int r = 0; r < 4; ++r)                            \
        acc[4 + r][t] = __builtin_amdgcn_mfma_f32_16x16x32_bf16(a1_[r], b_[t], \
                                                            acc[4 + r][t], 0, 0, 0);\
    __builtin_amdgcn_s_setprio(0);                                             \
    asm volatile("" ::: "memory");                                             \
    __builtin_amdgcn_s_barrier();                                              \
  } while (0)

  for (int ch = 0; ch < 16; ++ch) {
    const bool lc = (ch == 15);
    for (int k3 = 0; k3 < 12; ++k3) {
      const int kk = k3 * 3;   // 36 % 3 == 0 -> every chunk starts at buf 0
      // DRAIN at ch==15, kk>=34: no new stages are issued there, so the
      // steady-state vmcnt(4) would no longer guard stage 35's landing.
      G2_KK(kk + 0, 0, 2, false);
      G2_KK(kk + 1, 1, 0, (lc && k3 == 11));
      G2_KK(kk + 2, 2, 1, (lc && k3 == 11));
    }

    // ---- epilogue: 4 o-planes. acc rows = 128wm+16r+4q+i, c = 16t+l15,
    // o = 4ch+wn. (__syncthreads drains vmcnt once per chunk - amortized.)
    float b2v[4];
#pragma unroll
    for (int t = 0; t < 4; ++t) b2v[t] = b2[(16 * t + l15) * 64 + 4 * ch + wn];

    for (int p = 0; p < 4; ++p) {
      __syncthreads();           // w2buf free (prior plane's reads done)
      if (wn == p) {
#pragma unroll
        for (int r = 0; r < 8; ++r)
#pragma unroll
          for (int t = 0; t < 4; ++t)
#pragma unroll
            for (int i = 0; i < 4; ++i)
              w2buf[(128 * wm + 16 * r + 4 * q + i) * 68 + 16 * t + l15] =
                  f2bf(acc[r][t][i] + b2v[t]);
      }
      __syncthreads();
#pragma unroll
      for (int it = 0; it < 2; ++it) {
        const int row = 128 * it + 16 * wv + l15;   // 0..255, distinct/wave
        const size_t P = (size_t)bm * 256 + row;
        const float4v* y4 = (const float4v*)(yr + P * 64 + 16 * part);
        const float4v* m4 = (const float4v*)(mr + P * 64 + 16 * part);
        const float4v* s4 = (const float4v*)(sr + P * 64 + 16 * part);
        const ushort4v* w4 = (const ushort4v*)&w2buf[row * 68 + 16 * part];
        float ys = 0.f, ms = 0.f, ss = 0.f;
#pragma unroll
        for (int j4 = 0; j4 < 4; ++j4) {
          float4v yv = y4[j4], mv = m4[j4], sv = s4[j4];
          ushort4v wq = w4[j4];
#pragma unroll
          for (int j = 0; j < 4; ++j) {
            float w2f = bf2f(wq[j]);
            float aw  = fabsf(w2f);
            ys += yv[j] * w2f;
            ms += mv[j] * aw;
            ss += sv[j] * aw;
          }
        }
        ys += __shfl_xor(ys, 16); ys += __shfl_xor(ys, 32);
        ms += __shfl_xor(ms, 16); ms += __shfl_xor(ms, 32);
        ss += __shfl_xor(ss, 16); ss += __shfl_xor(ss, 32);
        if (part == 0) {
          const int o = 4 * ch + p;
          const int b = (int)(P >> 14), h = (int)((P >> 7) & 127), w = (int)(P & 127);
          size_t idx = ((size_t)((b << 6) | o) << 14) + (h << 7) + w;
          out[idx]           = ys;
          out[4194304 + idx] = ms / ss;
          out[8388608 + idx] = 1.0f;
        }
      }
    }
    // reset accumulators for next chunk
#pragma unroll
    for (int r = 0; r < 8; ++r)
#pragma unroll
      for (int t = 0; t < 4; ++t) acc[r][t] = (float4v){0.f, 0.f, 0.f, 0.f};
  }
#undef G2_KK
}

// ---------------------------------------------------------------------------
extern "C" void kernel_launch(void* const* d_in, const int* in_sizes, int n_in,
                              void* d_out, int out_size, void* d_ws, size_t ws_size,
                              hipStream_t stream) {
  const float* x  = (const float*)d_in[0];
  const float* m  = (const float*)d_in[1];
  const float* s  = (const float*)d_in[2];
  const float* W1 = (const float*)d_in[3];
  const float* b1 = (const float*)d_in[4];
  const float* W2 = (const float*)d_in[5];
  const float* b2 = (const float*)d_in[6];
  float* out = (float*)d_out;

  // ws layout (bytes):
  //   feat  bf16 : [0, 150994944)               36*65536*32 elems
  //   W1s   bf16 : [150994944, 152322048)       1152*576
  //   W2s   bf16 : [152322048, 161759232)       1152*4096 (o-major permuted)
  //   yr/mr/sr f32: 3 x 16777216 from 161759232 ; end = 212090880
  if (ws_size < 212090880ull) return;
  char* ws = (char*)d_ws;
  unsigned short* featb = (unsigned short*)ws;
  unsigned short* W1s   = (unsigned short*)(ws + 150994944);
  unsigned short* W2s   = (unsigned short*)(ws + 152322048);
  float* yr = (float*)(ws + 161759232);
  float* mr = (float*)(ws + 178536448);
  float* sr = (float*)(ws + 195313664);

  k_feat<<<294912, 256, 0, stream>>>(x, m, featb);
  k_sw<<<2592, 256, 0, stream>>>(W1, W1s, 576, 36, 663552, 0);
  k_sw<<<18432, 256, 0, stream>>>(W2, W2s, 4096, 256, 4718592, 1);
  dim3 g1(512, 4);
  k_gemm1<<<g1, 512, 0, stream>>>(featb, W1s, b1, x, m, s, yr, mr, sr);
  k_gemm2<<<256, 512, 0, stream>>>(featb, W2s, b2, yr, mr, sr, out);
}

// Round 5
// 1242.218 us; speedup vs baseline: 1.1187x; 1.1187x over previous
//
#include <hip/hip_runtime.h>
#include <stdint.h>
#include <stddef.h>

// Conv_M: fused dynamic-filter conv. B=4, Cin=Cout=64, H=W=128, K=3.
// R10: combine R7's counted-vmcnt single-barrier pipeline with 2 blocks/CU.
//   R9 post-mortem: rigid 2-phase split at 1 blk/CU REGRESSED (925 vs 848 µs)
//   - 4x barrier count with no second block to absorb convergence, and
//   lgkmcnt(0)+sched_barrier killed compiler's fine-grained overlap. R7's
//   remaining slack (~3.5k cyc/kk wall vs ~310 cyc MFMA) is TLP-starved.
//   Fix: BM=128 (512 blocks), 3x24KB LDS units (A 8KB + B 16KB per kk,
//   3 gll16/thread, vmcnt(3)), w2buf ALIASED into U[2] (dead at epilogue;
//   next U[2] write is behind next chunk's head barrier) -> 72KB LDS total
//   -> 2 blocks/CU. __launch_bounds__(512,4) caps VGPR at 128.
// k_feat / k_sw / k_gemm1 unchanged.

using short8   = __attribute__((ext_vector_type(8))) short;
using float4v  = __attribute__((ext_vector_type(4))) float;
using ushort4v = __attribute__((ext_vector_type(4))) unsigned short;

#define DI __device__ __forceinline__

DI unsigned short f2bf(float f) {
  union { float f; unsigned int u; } a; a.f = f;
  unsigned int r = a.u + 0x7fffu + ((a.u >> 16) & 1u);
  return (unsigned short)(r >> 16);
}
DI float bf2f(unsigned short u) {
  union { unsigned int u; float f; } a; a.u = ((unsigned int)u) << 16;
  return a.f;
}
DI void gll16(const void* g, void* l) {
  __builtin_amdgcn_global_load_lds(
      (const __attribute__((address_space(1))) unsigned int*)g,
      (__attribute__((address_space(3))) unsigned int*)l, 16, 0, 0);
}

// ---------------------------------------------------------------------------
// feat layout: idx = ((kk*512 + pblk)*4 + q)*1024 + plocal*8 + j8
//   kk = k/32 (36 blocks), pblk = pixel/128 (512), q = (k>>3)&3, j8 = k&7.
// feat col = c*9 + (kh*3+kw) for x (cols 0..575), same +576 for m.
// ---------------------------------------------------------------------------
__global__ void k_feat(const float* __restrict__ x, const float* __restrict__ m,
                       unsigned short* __restrict__ featb) {
  unsigned int tid = blockIdx.x * 256u + threadIdx.x;  // < 75,497,472
  int j8   = tid & 7;
  int pl   = (tid >> 3) & 127;
  int q    = (tid >> 10) & 3;
  int pblk = (tid >> 12) & 511;
  int kk   = tid >> 21;
  int col  = kk * 32 + q * 8 + j8;
  const float* src = x;
  int jx = col;
  if (col >= 576) { src = m; jx = col - 576; }
  int c  = jx / 9;
  int t  = jx - c * 9;
  int t3 = t / 3;
  int dh = t3 - 1;
  int dw = (t - t3 * 3) - 1;
  int p  = pblk * 128 + pl;
  int b  = p >> 14, h = (p >> 7) & 127, w = p & 127;
  int hh = min(max(h + dh, 0), 127);   // replicate pad
  int ww = min(max(w + dw, 0), 127);
  featb[tid] = f2bf(src[(((b << 6) | c) << 14) + (hh << 7) + ww]);
}

// Weight swizzle: src row-major [k][n] fp32 -> bf16 B-frag tiles at
//   idx = ((k>>5)*ntiles + (n'>>4))*512 + ((k>>3)&3)*128 + (n'&15)*8 + (k&7)
// perm=1 (W2): n' = (n&63)<<6 | (n>>6)  (o-major: n' = o*64 + c).
__global__ void k_sw(const float* __restrict__ Wsrc, unsigned short* __restrict__ Wdst,
                     int ncols, int ntiles, int total, int perm) {
  int tid = blockIdx.x * 256 + threadIdx.x;
  if (tid >= total) return;
  int k = tid / ncols;
  int n = tid - k * ncols;
  int np = perm ? (((n & 63) << 6) | (n >> 6)) : n;
  int out = ((k >> 5) * ntiles + (np >> 4)) * 512 + ((k >> 3) & 3) * 128 +
            (np & 15) * 8 + (k & 7);
  Wdst[out] = f2bf(Wsrc[tid]);
}

// ---------------------------------------------------------------------------
// GEMM1: w1 = feat@W1 + b1, then yr/mr/sr[p][c] via 3x3 taps on fp32 x/m/s.
// ---------------------------------------------------------------------------
__launch_bounds__(512, 2)
__global__ void k_gemm1(const unsigned short* __restrict__ featb,
                        const unsigned short* __restrict__ W1s,
                        const float* __restrict__ b1,
                        const float* __restrict__ x, const float* __restrict__ m,
                        const float* __restrict__ s,
                        float* __restrict__ yr, float* __restrict__ mr,
                        float* __restrict__ sr) {
  __shared__ __align__(16) unsigned short Alds[4096];       // 8KB  [q][p128][j8]
  __shared__ __align__(16) unsigned short Blds[4608];       // 9216B: 9 tiles
  __shared__ __align__(16) unsigned short w1buf[128 * 152]; // 38912B
  const int tid = threadIdx.x;
  const int wv  = tid >> 6;
  const int l15 = tid & 15;
  const int q   = (tid >> 4) & 3;
  const int bm  = blockIdx.x, nb = blockIdx.y;

  float4v acc[9];
#pragma unroll
  for (int t = 0; t < 9; ++t) acc[t] = (float4v){0.f, 0.f, 0.f, 0.f};

  const unsigned short* Ab = featb + (size_t)bm * 4096;
  const unsigned short* Bb = W1s + (size_t)nb * 9 * 512;

  for (int kk = 0; kk < 36; ++kk) {
    __syncthreads();
    gll16(Ab + (size_t)kk * 2097152 + tid * 8, (char*)Alds + wv * 1024);
    gll16(Bb + (size_t)kk * 18432 + tid * 8, (char*)Blds + wv * 1024);
    if (tid < 64) gll16(Bb + (size_t)kk * 18432 + 4096 + tid * 8, (char*)Blds + 8192);
    __syncthreads();
    short8 af = *(const short8*)&Alds[q * 1024 + (16 * wv + l15) * 8];
#pragma unroll
    for (int t = 0; t < 9; ++t) {
      short8 bfr = *(const short8*)&Blds[t * 512 + q * 128 + l15 * 8];
      acc[t] = __builtin_amdgcn_mfma_f32_16x16x32_bf16(af, bfr, acc[t], 0, 0, 0);
    }
  }

  // w1 (+bias) -> LDS as bf16. C/D layout: col=lane&15, row=quad*4+i.
#pragma unroll
  for (int t = 0; t < 9; ++t) {
    int col = 16 * t + l15;
    float bb = b1[nb * 144 + col];
#pragma unroll
    for (int i = 0; i < 4; ++i) {
      int plr = 16 * wv + 4 * q + i;
      w1buf[plr * 152 + col] = f2bf(acc[t][i] + bb);
    }
  }
  __syncthreads();

  const int b = bm >> 7, h = bm & 127;  // m-block = one (b,h) image row
#pragma unroll
  for (int ii = 0; ii < 4; ++ii) {
    int task = ii * 512 + tid;     // 2048 tasks: (p 0..127) x (cl 0..15)
    int p  = task >> 4;
    int cl = task & 15;
    int c  = nb * 16 + cl;
    float w1v[9];
#pragma unroll
    for (int k = 0; k < 9; ++k) w1v[k] = bf2f(w1buf[p * 152 + cl * 9 + k]);
    size_t base = (size_t)(((b << 6) | c) << 14);
    float vy = 0.f, vm = 0.f, vs = 0.f;
#pragma unroll
    for (int dh = -1; dh <= 1; ++dh) {
      int hh = min(max(h + dh, 0), 127);
#pragma unroll
      for (int dw = -1; dw <= 1; ++dw) {
        int ww = min(max(p + dw, 0), 127);
        size_t idx = base + (hh << 7) + ww;
        int k = (dh + 1) * 3 + (dw + 1);
        float wv1 = w1v[k], aw = fabsf(wv1);
        vy += x[idx] * wv1;
        vm += m[idx] * aw;
        vs += s[idx] * aw;
      }
    }
    size_t P = (size_t)bm * 128 + p;
    yr[P * 64 + c] = vy;
    mr[P * 64 + c] = vm;
    sr[P * 64 + c] = vs;
  }
}

// ---------------------------------------------------------------------------
// GEMM2 (R10): block = 128 rows x 256 cols/chunk, 16 chunks. 512 blocks,
// 2 blocks/CU (72KB LDS, 128-VGPR cap). 8 waves 2x4: wm = 64-row half,
// wn -> o = 4ch+wn. acc[4][4] = 64 regs. Per kk (K=32), R7-style single
// phase: vmcnt(3) -> s_barrier -> issue stage kk+2 (3 gll16: A 8KB, B 16KB)
// -> 8 ds_read_b128 -> 16 MFMA in setprio(1). Compiler inserts fine-grained
// lgkmcnt between ds_read and MFMA. vmcnt(3) at kk head guarantees stage kk
// landed (only stage kk+1's 3 loads remain). Buffers rotate kk%3; stage
// targets (kk+2)%3 = the buffer whose reads completed at kk-1 (reads are
// consumed before each wave's barrier arrival -> no read/write race).
// Epilogue per chunk: w2buf ALIASED onto U[2] (17.4KB <= 24KB). At epilogue,
// in-flight stages target U[0]/U[1] only; U[2]'s next write (stage kk'=0,
// issued inside next chunk's first step) is behind that step's head barrier,
// which all waves reach only after their last w2buf reads are consumed.
// Epilogue head __syncthreads drains vmcnt once per chunk (amortized 1/36).
// ---------------------------------------------------------------------------
__launch_bounds__(512, 4)
__global__ void k_gemm2(const unsigned short* __restrict__ featb,
                        const unsigned short* __restrict__ W2s,
                        const float* __restrict__ b2,
                        const float* __restrict__ yr, const float* __restrict__ mr,
                        const float* __restrict__ sr,
                        float* __restrict__ out) {
  __shared__ __align__(16) unsigned short U[3][12288];  // 3 x 24KB: [A 4096 | B 8192] shorts
  unsigned short* w2buf = &U[2][0];                     // aliased: 128*68 = 8704 shorts
  const int tid  = threadIdx.x;
  const int wv   = tid >> 6;     // 0..7
  const int lane = tid & 63;
  const int wm   = wv >> 2;      // 0..1: 64-row half
  const int wn   = wv & 3;       // 0..3: o = 4ch+wn
  const int l15  = tid & 15;
  const int q    = (tid >> 4) & 3;
  const int part = lane >> 4;    // 0..3: 16-c quarter (epilogue)
  const int bm   = blockIdx.x;   // 0..511: rows 128bm..128bm+127 (pblk = bm)

  const unsigned short* Ab = featb + (size_t)bm * 4096;

  float4v acc[4][4];
#pragma unroll
  for (int r = 0; r < 4; ++r)
#pragma unroll
    for (int t = 0; t < 4; ++t) acc[r][t] = (float4v){0.f, 0.f, 0.f, 0.f};

  // prologue: stage kk=0 -> U[0], kk=1 -> U[1]  (3 gll16 each)
  gll16(Ab + tid * 8,                  (char*)&U[0][0]    + wv * 1024);
  gll16(W2s + tid * 8,                 (char*)&U[0][4096] + wv * 1024);
  gll16(W2s + 4096 + tid * 8,          (char*)&U[0][8192] + wv * 1024);
  gll16(Ab + 2097152 + tid * 8,        (char*)&U[1][0]    + wv * 1024);
  gll16(W2s + 131072 + tid * 8,        (char*)&U[1][4096] + wv * 1024);
  gll16(W2s + 131072 + 4096 + tid * 8, (char*)&U[1][8192] + wv * 1024);

#define G2_KK(KK, BR, BS, DRAIN)                                               \
  do {                                                                         \
    int kks = (KK) + 2, chs = ch;                                              \
    if (kks >= 36) { kks -= 36; chs += 1; }                                    \
    if (DRAIN) { asm volatile("s_waitcnt vmcnt(0)" ::: "memory"); }            \
    else       { asm volatile("s_waitcnt vmcnt(3)" ::: "memory"); }            \
    __builtin_amdgcn_s_barrier();                                              \
    asm volatile("" ::: "memory");                                             \
    if (chs < 16) {                                                            \
      const unsigned short* Ag = Ab + (size_t)kks * 2097152;                   \
      const unsigned short* Bg = W2s + (size_t)kks * 131072 + (size_t)chs * 8192; \
      gll16(Ag + tid * 8,        (char*)&U[BS][0]    + wv * 1024);             \
      gll16(Bg + tid * 8,        (char*)&U[BS][4096] + wv * 1024);             \
      gll16(Bg + 4096 + tid * 8, (char*)&U[BS][8192] + wv * 1024);             \
    }                                                                          \
    {                                                                          \
      const unsigned short* Al = &U[BR][0];                                    \
      const unsigned short* Bl = &U[BR][4096];                                 \
      short8 a_[4];                                                            \
      _Pragma("unroll") for (int r = 0; r < 4; ++r)                            \
        a_[r] = *(const short8*)&Al[q * 1024 + (64 * wm + 16 * r + l15) * 8];  \
      __builtin_amdgcn_s_setprio(1);                                           \
      _Pragma("unroll") for (int t = 0; t < 4; ++t) {                          \
        short8 bfr = *(const short8*)&Bl[(4 * wn + t) * 512 + q * 128 + l15 * 8]; \
        _Pragma("unroll") for (int r = 0; r < 4; ++r)                          \
          acc[r][t] = __builtin_amdgcn_mfma_f32_16x16x32_bf16(a_[r], bfr,      \
                                                              acc[r][t], 0, 0, 0); \
      }                                                                        \
      __builtin_amdgcn_s_setprio(0);                                           \
    }                                                                          \
  } while (0)

  for (int ch = 0; ch < 16; ++ch) {
    const bool lc = (ch == 15);
    for (int k3 = 0; k3 < 12; ++k3) {
      const int kk = k3 * 3;   // 36 % 3 == 0 -> every chunk starts at buf 0
      // DRAIN at ch==15, kk>=34: no new stages issued there, so vmcnt(3)
      // would no longer guard stage 35's landing.
      G2_KK(kk + 0, 0, 2, false);
      G2_KK(kk + 1, 1, 0, (lc && k3 == 11));
      G2_KK(kk + 2, 2, 1, (lc && k3 == 11));
    }

    // ---- epilogue: 4 o-planes via w2buf (= U[2], dead until next chunk's
    // first stage-issue, which is behind that step's head barrier).
    // acc rows = 64wm+16r+4q+i, c = 16t+l15, o = 4ch+wn.
    float b2v[4];
#pragma unroll
    for (int t = 0; t < 4; ++t) b2v[t] = b2[(16 * t + l15) * 64 + 4 * ch + wn];

    for (int p = 0; p < 4; ++p) {
      __syncthreads();           // w2buf free (K-loop reads / prior plane done)
      if (wn == p) {
#pragma unroll
        for (int r = 0; r < 4; ++r)
#pragma unroll
          for (int t = 0; t < 4; ++t)
#pragma unroll
            for (int i = 0; i < 4; ++i)
              w2buf[(64 * wm + 16 * r + 4 * q + i) * 68 + 16 * t + l15] =
                  f2bf(acc[r][t][i] + b2v[t]);
      }
      __syncthreads();
      // all waves: row = 16wv + l15 (128 distinct rows), quarter = part
      const int row = 16 * wv + l15;
      const size_t P = (size_t)bm * 128 + row;
      const float4v* y4 = (const float4v*)(yr + P * 64 + 16 * part);
      const float4v* m4 = (const float4v*)(mr + P * 64 + 16 * part);
      const float4v* s4 = (const float4v*)(sr + P * 64 + 16 * part);
      const ushort4v* w4 = (const ushort4v*)&w2buf[row * 68 + 16 * part];
      float ys = 0.f, ms = 0.f, ss = 0.f;
#pragma unroll
      for (int j4 = 0; j4 < 4; ++j4) {
        float4v yv = y4[j4], mv = m4[j4], sv = s4[j4];
        ushort4v wq = w4[j4];
#pragma unroll
        for (int j = 0; j < 4; ++j) {
          float w2f = bf2f(wq[j]);
          float aw  = fabsf(w2f);
          ys += yv[j] * w2f;
          ms += mv[j] * aw;
          ss += sv[j] * aw;
        }
      }
      ys += __shfl_xor(ys, 16); ys += __shfl_xor(ys, 32);
      ms += __shfl_xor(ms, 16); ms += __shfl_xor(ms, 32);
      ss += __shfl_xor(ss, 16); ss += __shfl_xor(ss, 32);
      if (part == 0) {
        const int o = 4 * ch + p;
        const int b = (int)(P >> 14), h = (int)((P >> 7) & 127), w = (int)(P & 127);
        size_t idx = ((size_t)((b << 6) | o) << 14) + (h << 7) + w;
        out[idx]           = ys;
        out[4194304 + idx] = ms / ss;
        out[8388608 + idx] = 1.0f;
      }
    }
    // reset accumulators for next chunk
#pragma unroll
    for (int r = 0; r < 4; ++r)
#pragma unroll
      for (int t = 0; t < 4; ++t) acc[r][t] = (float4v){0.f, 0.f, 0.f, 0.f};
  }
#undef G2_KK
}

// ---------------------------------------------------------------------------
extern "C" void kernel_launch(void* const* d_in, const int* in_sizes, int n_in,
                              void* d_out, int out_size, void* d_ws, size_t ws_size,
                              hipStream_t stream) {
  const float* x  = (const float*)d_in[0];
  const float* m  = (const float*)d_in[1];
  const float* s  = (const float*)d_in[2];
  const float* W1 = (const float*)d_in[3];
  const float* b1 = (const float*)d_in[4];
  const float* W2 = (const float*)d_in[5];
  const float* b2 = (const float*)d_in[6];
  float* out = (float*)d_out;

  // ws layout (bytes):
  //   feat  bf16 : [0, 150994944)               36*65536*32 elems
  //   W1s   bf16 : [150994944, 152322048)       1152*576
  //   W2s   bf16 : [152322048, 161759232)       1152*4096 (o-major permuted)
  //   yr/mr/sr f32: 3 x 16777216 from 161759232 ; end = 212090880
  if (ws_size < 212090880ull) return;
  char* ws = (char*)d_ws;
  unsigned short* featb = (unsigned short*)ws;
  unsigned short* W1s   = (unsigned short*)(ws + 150994944);
  unsigned short* W2s   = (unsigned short*)(ws + 152322048);
  float* yr = (float*)(ws + 161759232);
  float* mr = (float*)(ws + 178536448);
  float* sr = (float*)(ws + 195313664);

  k_feat<<<294912, 256, 0, stream>>>(x, m, featb);
  k_sw<<<2592, 256, 0, stream>>>(W1, W1s, 576, 36, 663552, 0);
  k_sw<<<18432, 256, 0, stream>>>(W2, W2s, 4096, 256, 4718592, 1);
  dim3 g1(512, 4);
  k_gemm1<<<g1, 512, 0, stream>>>(featb, W1s, b1, x, m, s, yr, mr, sr);
  k_gemm2<<<512, 512, 0, stream>>>(featb, W2s, b2, yr, mr, sr, out);
}